// Round 8
// baseline (248.508 us; speedup 1.0000x reference)
//
#include <hip/hip_runtime.h>
#include <hip/hip_bf16.h>
#include <cstdint>

#define KDIM 1024
#define BDIM 8192
#define VDIM 2
#define NBLK 16  // KDIM / 64

#if defined(__has_builtin)
#if __has_builtin(__builtin_amdgcn_global_load_lds)
#define HAS_GLL 1
#endif
#endif
#ifndef HAS_GLL
#define HAS_GLL 0
#endif

typedef __attribute__((ext_vector_type(8))) short short8;
typedef __attribute__((ext_vector_type(4))) float f32x4;

__device__ inline unsigned short f2bf(float x) {
  unsigned u = __builtin_bit_cast(unsigned, x);
  u = (u + 0x7FFFu + ((u >> 16) & 1u)) >> 16;
  return (unsigned short)u;
}

__device__ inline float bf2f(unsigned short x) {
  return __builtin_bit_cast(float, (unsigned)x << 16);
}

// ---------------------------------------------------------------------------
// Workspace layout (bytes from d_ws):
//   MT   @ 0        4 MB fp32   M^T (MT[t][i] = M[i][t])
//   Mbf  @ 4 MB     2 MB bf16   M row-major (Mbf[i][k] = M[i][k])
//   Pt2  @ 6 MB     0.5 MB      lv2 P scratch
//   Pt3  @ 6.5 MB   1 MB        lv3 P scratch
//   Zbf  @ 7.5 MB   16 MB       Z in bf16
// ---------------------------------------------------------------------------

// --------------------------- shared tile helpers ---------------------------
#define STAGE_T(DST, SRC, ROW0, COL0, LD)                                   \
  {                                                                         \
    const float* _s = (SRC);                                                \
    _Pragma("unroll") for (int _p = 0; _p < 4; ++_p) {                      \
      const int _m = _p * 16 + rw;                                          \
      float4 _v = *(const float4*)(_s + (size_t)((ROW0) + _m) * (LD) +      \
                                   (COL0) + 4 * k4);                        \
      (DST)[4 * k4 + 0][_m] = _v.x;                                         \
      (DST)[4 * k4 + 1][_m] = _v.y;                                         \
      (DST)[4 * k4 + 2][_m] = _v.z;                                         \
      (DST)[4 * k4 + 3][_m] = _v.w;                                         \
    }                                                                       \
  }

#define STAGE_D(DST, SRC, ROW0, COL0, LD)                                   \
  {                                                                         \
    const float* _s = (SRC);                                                \
    _Pragma("unroll") for (int _p = 0; _p < 4; ++_p) {                      \
      const int _kk = _p * 16 + rw;                                         \
      *(float4*)&(DST)[_kk][4 * k4] =                                       \
          *(const float4*)(_s + (size_t)((ROW0) + _kk) * (LD) + (COL0) +    \
                           4 * k4);                                         \
    }                                                                       \
  }

// T14 pipeline pieces: LOADR = global -> 4x float4 regs (same addresses as
// STAGE_T/STAGE_D); WRT_T / WRT_D = regs -> LDS in the two layouts.
#define LOADR(REG, SRC, ROW0, COL0, LD)                                     \
  _Pragma("unroll") for (int _p = 0; _p < 4; ++_p) {                        \
    (REG)[_p] = *(const float4*)((SRC) +                                    \
                                 (size_t)((ROW0) + _p * 16 + rw) * (LD) +   \
                                 (COL0) + 4 * k4);                          \
  }

#define WRT_T(DST, REG)                                                     \
  _Pragma("unroll") for (int _p = 0; _p < 4; ++_p) {                        \
    const int _m = _p * 16 + rw;                                            \
    (DST)[4 * k4 + 0][_m] = (REG)[_p].x;                                    \
    (DST)[4 * k4 + 1][_m] = (REG)[_p].y;                                    \
    (DST)[4 * k4 + 2][_m] = (REG)[_p].z;                                    \
    (DST)[4 * k4 + 3][_m] = (REG)[_p].w;                                    \
  }

#define WRT_D(DST, REG)                                                     \
  _Pragma("unroll") for (int _p = 0; _p < 4; ++_p) {                        \
    *(float4*)&(DST)[_p * 16 + rw][4 * k4] = (REG)[_p];                     \
  }

#define ZERO_ACC                                                            \
  _Pragma("unroll") for (int _a = 0; _a < 4; ++_a)                          \
      _Pragma("unroll") for (int _b = 0; _b < 4; ++_b) acc[_a][_b] = 0.f;

__device__ __forceinline__ void mac64(const float (*Ls)[68],
                                      const float (*Rs)[68], int tm, int tn,
                                      float acc[4][4]) {
#pragma unroll 4
  for (int k = 0; k < 64; ++k) {
    const float4 av = *(const float4*)&Ls[k][4 * tm];
    const float4 bv = *(const float4*)&Rs[k][4 * tn];
    const float aa[4] = {av.x, av.y, av.z, av.w};
    const float bb4[4] = {bv.x, bv.y, bv.z, bv.w};
#pragma unroll
    for (int a = 0; a < 4; ++a)
#pragma unroll
      for (int b = 0; b < 4; ++b) acc[a][b] += aa[a] * bb4[b];
  }
}

#define STORE_MT(R0, C0)                                                    \
  _Pragma("unroll") for (int _a = 0; _a < 4; ++_a) {                        \
    *(float4*)(MT + (size_t)((R0) + 4 * tm + _a) * KDIM + (C0) + 4 * tn) =  \
        make_float4(acc[_a][0], acc[_a][1], acc[_a][2], acc[_a][3]);        \
  }

#define MBF_TILE(R0, C0, BUF)                                               \
  {                                                                         \
    __syncthreads();                                                        \
    _Pragma("unroll") for (int _a = 0; _a < 4; ++_a)                        \
        _Pragma("unroll") for (int _b = 0; _b < 4; ++_b)                    \
            (BUF)[4 * tm + _a][4 * tn + _b] = acc[_a][_b];                  \
    __syncthreads();                                                        \
    const int _tr = tid >> 4, _tc = tid & 15;                               \
    _Pragma("unroll") for (int _p = 0; _p < 4; ++_p) {                      \
      const int _il = _p * 16 + _tr;                                        \
      ushort4 _o;                                                           \
      _o.x = f2bf((BUF)[4 * _tc + 0][_il]);                                 \
      _o.y = f2bf((BUF)[4 * _tc + 1][_il]);                                 \
      _o.z = f2bf((BUF)[4 * _tc + 2][_il]);                                 \
      _o.w = f2bf((BUF)[4 * _tc + 3][_il]);                                 \
      *(ushort4*)(Mbf + (size_t)((C0) + _il) * KDIM + (R0) + 4 * _tc) = _o; \
    }                                                                       \
  }

// ---------------------------------------------------------------------------
// comb01 (grid 256): blocks 0..15 = verified phase-0 (split-32 inversion) +
// verified lv0/lv1 body. Blocks 16..255 = streaming moved from p4_stream
// (MT strict-lower zero, Mbf strict-upper zero, Z->bf16) — all regions
// disjoint from comb01's tile writes, so concurrent execution is safe, and
// it fills the 240 CUs that previously idled under comb01's 50 us window.
// ---------------------------------------------------------------------------
__global__ __launch_bounds__(256) void comb01(const float* __restrict__ A,
                                              float* __restrict__ MT,
                                              unsigned short* __restrict__ Mbf,
                                              const float* __restrict__ Z,
                                              unsigned short* __restrict__ Zbf,
                                              int do_zbf) {
  if (blockIdx.x >= NBLK) {
    const int wid = blockIdx.x - NBLK;
    const int nw = gridDim.x - NBLK;
    const int idx0 = wid * 256 + threadIdx.x;
    const int stride = nw * 256;
    const float4 z4 = make_float4(0.f, 0.f, 0.f, 0.f);
    const uint4 u4 = make_uint4(0u, 0u, 0u, 0u);

    for (int i = idx0; i < 256 * 1024; i += stride) {
      const int blk = i >> 10, off = i & 1023;
      const int bi = blk >> 4, bj = blk & 15;
      if (bi <= bj) continue;  // strict-lower MT blocks only
      *(float4*)(MT + (size_t)(bi * 64 + (off >> 4)) * KDIM + bj * 64 +
                 4 * (off & 15)) = z4;
    }
    for (int i = idx0; i < 256 * 512; i += stride) {
      const int blk = i >> 9, off = i & 511;
      const int bi = blk >> 4, bj = blk & 15;
      if (bi >= bj) continue;  // strict-upper Mbf blocks only
      *(uint4*)(Mbf + (size_t)(bi * 64 + (off >> 3)) * KDIM + bj * 64 +
                8 * (off & 7)) = u4;
    }
    if (do_zbf) {
      for (int i = idx0; i < BDIM * KDIM / 4; i += stride) {
        float4 v = *(const float4*)(Z + 4 * (size_t)i);
        ushort4 o;
        o.x = f2bf(v.x);
        o.y = f2bf(v.y);
        o.z = f2bf(v.z);
        o.w = f2bf(v.w);
        *(ushort4*)(Zbf + 4 * (size_t)i) = o;
      }
    }
    return;
  }

  int b = blockIdx.x;
  const int rt = b & 1;
  const int jt = (b >> 1) & 1;
  const int s = b >> 2;
  const int base = s * 256;

  __shared__ float shpool[6 * 64 * 68];
  float (*Ls)[68] = (float(*)[68])(shpool);
  float (*Rs)[68] = (float(*)[68])(shpool + 4352);
  float (*tQ0L)[68] = (float(*)[68])(shpool + 2 * 4352);
  float (*tQ0H)[68] = (float(*)[68])(shpool + 3 * 4352);
  float (*tP0)[68] = (float(*)[68])(shpool + 4 * 4352);
  float (*tP1)[68] = (float(*)[68])(shpool + 5 * 4352);

  const int tid = threadIdx.x;
  const int k4 = tid & 15;
  const int rw = tid >> 4;
  const int tm = tid >> 4;
  const int tn = tid & 15;
  float acc[4][4];

  // ---- phase 0: invert the 4 diagonal blocks (split-32 + combine) ----
  {
    float* Tt = shpool;              // Tt[g][h][r][c] = g*2112 + h*1056 + r*33 + c
    float* As4 = shpool + 2 * 4352;  // 4 x [64][65]
    const int g = tid >> 6;          // wave -> diagonal 4s+g
    const int l = tid & 63;
    const int dbase = base + g * 64;
    float* Asg = As4 + g * 4160;

    for (int r = 0; r < 64; ++r)
      Asg[r * 65 + l] = A[(size_t)(dbase + r) * KDIM + dbase + l];
    __syncthreads();

    {
      const int h = l >> 5, c = l & 31;
      const float* Ah = Asg + (32 * h) * 65 + 32 * h;
      float m[32];
#pragma unroll
      for (int r = 0; r < 32; ++r) m[r] = (r == c) ? 1.f : 0.f;
#pragma unroll
      for (int r = 1; r < 32; ++r) {
        float a0 = 0.f, a1 = 0.f;
#pragma unroll
        for (int i = 0; i < 32; ++i) {
          if (i >= r) break;
          if (i & 1) a1 += Ah[r * 65 + i] * m[i];
          else       a0 += Ah[r * 65 + i] * m[i];
        }
        const float v = a0 + a1;
        m[r] = (r > c) ? v : m[r];
      }
      float* Th = Tt + g * 2112 + h * 1056;
#pragma unroll
      for (int r = 0; r < 32; ++r) Th[r * 33 + c] = m[r];
    }
    __syncthreads();

    const int tm8 = l >> 3, tn8 = l & 7;
    {
      float u[4][4];
#pragma unroll
      for (int a = 0; a < 4; ++a)
#pragma unroll
        for (int b2 = 0; b2 < 4; ++b2) u[a][b2] = 0.f;
      const float* T1 = Tt + g * 2112;
#pragma unroll
      for (int ki = 0; ki < 8; ++ki) {
        float4 av[4], bv[4];
#pragma unroll
        for (int a = 0; a < 4; ++a)
          av[a] = *(const float4*)&Asg[(32 + 4 * tm8 + a) * 65 + 4 * ki];
#pragma unroll
        for (int j = 0; j < 4; ++j)
          bv[j] = *(const float4*)&T1[(4 * ki + j) * 33 + 4 * tn8];
#pragma unroll
        for (int a = 0; a < 4; ++a) {
          const float aa[4] = {av[a].x, av[a].y, av[a].z, av[a].w};
#pragma unroll
          for (int j = 0; j < 4; ++j) {
            const float bb[4] = {bv[j].x, bv[j].y, bv[j].z, bv[j].w};
#pragma unroll
            for (int b2 = 0; b2 < 4; ++b2) u[a][b2] += aa[j] * bb[b2];
          }
        }
      }
#pragma unroll
      for (int a = 0; a < 4; ++a)
#pragma unroll
        for (int b2 = 0; b2 < 4; ++b2)
          Asg[(4 * tm8 + a) * 32 + 4 * tn8 + b2] = u[a][b2];
    }
    __syncthreads();

    {
      float t21[4][4];
#pragma unroll
      for (int a = 0; a < 4; ++a)
#pragma unroll
        for (int b2 = 0; b2 < 4; ++b2) t21[a][b2] = 0.f;
      const float* T2 = Tt + g * 2112 + 1056;
#pragma unroll
      for (int ki = 0; ki < 8; ++ki) {
        float4 av[4], bv[4];
#pragma unroll
        for (int a = 0; a < 4; ++a)
          av[a] = *(const float4*)&T2[(4 * tm8 + a) * 33 + 4 * ki];
#pragma unroll
        for (int j = 0; j < 4; ++j)
          bv[j] = *(const float4*)&Asg[(4 * ki + j) * 32 + 4 * tn8];
#pragma unroll
        for (int a = 0; a < 4; ++a) {
          const float aa[4] = {av[a].x, av[a].y, av[a].z, av[a].w};
#pragma unroll
          for (int j = 0; j < 4; ++j) {
            const float bb[4] = {bv[j].x, bv[j].y, bv[j].z, bv[j].w};
#pragma unroll
            for (int b2 = 0; b2 < 4; ++b2) t21[a][b2] += aa[j] * bb[b2];
          }
        }
      }
#pragma unroll
      for (int a = 0; a < 4; ++a)
#pragma unroll
        for (int b2 = 0; b2 < 4; ++b2)
          Asg[1024 + (4 * tm8 + a) * 32 + 4 * tn8 + b2] = t21[a][b2];
    }
    __syncthreads();

    {
      const float* T21 = Asg + 1024;
      const float* Tg = Tt + g * 2112;
      for (int r4 = 0; r4 < 16; ++r4) {
        float vals[4];
#pragma unroll
        for (int j = 0; j < 4; ++j) {
          const int r = 4 * r4 + j;
          float v;
          if (r < 32)
            v = (l < 32) ? Tg[r * 33 + l] : 0.f;
          else
            v = (l < 32) ? T21[(r - 32) * 32 + l]
                         : Tg[1056 + (r - 32) * 33 + (l - 32)];
          vals[j] = v;
        }
        *(float4*)(MT + (size_t)(dbase + l) * KDIM + dbase + 4 * r4) =
            make_float4(vals[0], vals[1], vals[2], vals[3]);
      }
      if (jt == 0 && rt == 0) {
        for (int r = 0; r < 64; ++r) {
          float v;
          if (r < 32)
            v = (l < 32) ? Tg[r * 33 + l] : 0.f;
          else
            v = (l < 32) ? T21[(r - 32) * 32 + l]
                         : Tg[1056 + (r - 32) * 33 + (l - 32)];
          Mbf[(size_t)(dbase + r) * KDIM + dbase + l] = f2bf(v);
        }
      }
    }
    __syncthreads();
  }

  // ---- verified comb01 body (rounds 3-7) ----
  if (jt == 0) {
    STAGE_T(Ls, MT, base, base, KDIM);
    STAGE_T(Rs, A, base + 64, base, KDIM);
    __syncthreads();
    ZERO_ACC;
    mac64(Ls, Rs, tm, tn, acc);
    __syncthreads();
#pragma unroll
    for (int a = 0; a < 4; ++a)
#pragma unroll
      for (int b2 = 0; b2 < 4; ++b2) tP0[4 * tn + b2][4 * tm + a] = acc[a][b2];
    STAGE_D(Rs, MT, base + 64, base + 64, KDIM);
    __syncthreads();
    ZERO_ACC;
    mac64(tP0, Rs, tm, tn, acc);
    __syncthreads();
#pragma unroll
    for (int a = 0; a < 4; ++a)
#pragma unroll
      for (int b2 = 0; b2 < 4; ++b2) tQ0L[4 * tn + b2][4 * tm + a] = acc[a][b2];
    if (rt == 0) {
      STORE_MT(base, base + 64);
      MBF_TILE(base, base + 64, Rs);
    }
  }
  __syncthreads();

  if (rt == 1) {
    STAGE_T(Ls, MT, base + 128, base + 128, KDIM);
    STAGE_T(Rs, A, base + 192, base + 128, KDIM);
    __syncthreads();
    ZERO_ACC;
    mac64(Ls, Rs, tm, tn, acc);
    __syncthreads();
#pragma unroll
    for (int a = 0; a < 4; ++a)
#pragma unroll
      for (int b2 = 0; b2 < 4; ++b2) tP1[4 * tn + b2][4 * tm + a] = acc[a][b2];
    STAGE_D(Rs, MT, base + 192, base + 192, KDIM);
    __syncthreads();
    ZERO_ACC;
    mac64(tP1, Rs, tm, tn, acc);
    __syncthreads();
#pragma unroll
    for (int a = 0; a < 4; ++a)
#pragma unroll
      for (int b2 = 0; b2 < 4; ++b2) tQ0H[4 * tm + a][4 * tn + b2] = acc[a][b2];
    if (jt == 1) {
      STORE_MT(base + 128, base + 192);
      MBF_TILE(base + 128, base + 192, Rs);
    }
  }
  __syncthreads();

  STAGE_T(Ls, MT, base + 64 * jt, base + 64 * jt, KDIM);
  __syncthreads();
  for (int kb2 = 0; kb2 <= rt; ++kb2) {
    ZERO_ACC;
    for (int kb = jt; kb < 2; ++kb) {
      STAGE_T(Rs, A, base + 128 + 64 * kb2, base + 64 * kb, KDIM);
      __syncthreads();
      mac64(kb == jt ? Ls : tQ0L, Rs, tm, tn, acc);
      __syncthreads();
    }
    if (kb2 == 0) {
#pragma unroll
      for (int a = 0; a < 4; ++a)
#pragma unroll
        for (int b2 = 0; b2 < 4; ++b2) tP0[4 * tn + b2][4 * tm + a] = acc[a][b2];
    } else {
#pragma unroll
      for (int a = 0; a < 4; ++a)
#pragma unroll
        for (int b2 = 0; b2 < 4; ++b2) tP1[4 * tn + b2][4 * tm + a] = acc[a][b2];
    }
  }
  __syncthreads();

  ZERO_ACC;
  if (rt == 0) {
    STAGE_D(Rs, MT, base + 128, base + 128, KDIM);
    __syncthreads();
    mac64(tP0, Rs, tm, tn, acc);
    __syncthreads();
  } else {
    mac64(tP0, tQ0H, tm, tn, acc);
    __syncthreads();
    STAGE_D(Rs, MT, base + 192, base + 192, KDIM);
    __syncthreads();
    mac64(tP1, Rs, tm, tn, acc);
    __syncthreads();
  }
  STORE_MT(base + 64 * jt, base + 128 + 64 * rt);
  MBF_TILE(base + 64 * jt, base + 128 + 64 * rt, Rs);
}

// ---------------------------------------------------------------------------
// p_k<T>: lv P tiles with T14 software pipeline — next iteration's global
// loads are issued before the current mac64, hiding HBM/L2 latency under
// compute (these kernels run 1 block/CU, 4 waves: latency-bound).
// grid: T=4 -> 32, T=8 -> 64.
// ---------------------------------------------------------------------------
template <int T>
__global__ __launch_bounds__(256) void p_k(const float* __restrict__ A,
                                           const float* __restrict__ MT,
                                           float* __restrict__ Pt) {
  int b = blockIdx.x;
  const int rb = b % T; b /= T;
  const int jb = b % T; b /= T;
  const int c = b;
  const int h = 64 * T;
  const int base = c * 2 * h;

  __shared__ float Ls[64][68];
  __shared__ float Rs[64][68];
  const int tid = threadIdx.x;
  const int k4 = tid & 15;
  const int rw = tid >> 4;
  const int tm = tid >> 4;
  const int tn = tid & 15;
  float acc[4][4];
  ZERO_ACC;

  float4 lr[4], rr[4];
  LOADR(lr, MT, base + 64 * jb, base + 64 * jb, KDIM);
  LOADR(rr, A, base + h + 64 * rb, base + 64 * jb, KDIM);
  for (int kb = jb; kb < T; ++kb) {
    WRT_T(Ls, lr);
    WRT_T(Rs, rr);
    __syncthreads();
    if (kb + 1 < T) {
      LOADR(lr, MT, base + 64 * jb, base + 64 * (kb + 1), KDIM);
      LOADR(rr, A, base + h + 64 * rb, base + 64 * (kb + 1), KDIM);
    }
    mac64(Ls, Rs, tm, tn, acc);
    __syncthreads();
  }

  float* P0 = Pt + (size_t)c * h * h;
#pragma unroll
  for (int a = 0; a < 4; ++a)
    *(float4*)(P0 + (size_t)(64 * jb + 4 * tm + a) * h + 64 * rb + 4 * tn) =
        make_float4(acc[a][0], acc[a][1], acc[a][2], acc[a][3]);
}

// ---------------------------------------------------------------------------
// q_k<T>: Q tiles + Mbf mirror, same T14 pipeline.
// ---------------------------------------------------------------------------
template <int T>
__global__ __launch_bounds__(256) void q_k(float* __restrict__ MT,
                                           const float* __restrict__ Pt,
                                           unsigned short* __restrict__ Mbf) {
  int b = blockIdx.x;
  const int rb = b % T; b /= T;
  const int jb = b % T; b /= T;
  const int c = b;
  const int h = 64 * T;
  const int base = c * 2 * h;

  __shared__ float Ls[64][68];
  __shared__ float Rs[64][68];
  const int tid = threadIdx.x;
  const int k4 = tid & 15;
  const int rw = tid >> 4;
  const int tm = tid >> 4;
  const int tn = tid & 15;
  float acc[4][4];
  ZERO_ACC;

  const float* P0 = Pt + (size_t)c * h * h;
  float4 lr[4], rr[4];
  LOADR(lr, P0, 64 * jb, 0, h);
  LOADR(rr, MT, base + h, base + h + 64 * rb, KDIM);
  for (int kb = 0; kb <= rb; ++kb) {
    WRT_T(Ls, lr);
    WRT_D(Rs, rr);
    __syncthreads();
    if (kb + 1 <= rb) {
      LOADR(lr, P0, 64 * jb, 64 * (kb + 1), h);
      LOADR(rr, MT, base + h + 64 * (kb + 1), base + h + 64 * rb, KDIM);
    }
    mac64(Ls, Rs, tm, tn, acc);
    __syncthreads();
  }

  STORE_MT(base + 64 * jb, base + h + 64 * rb);
  MBF_TILE(base + 64 * jb, base + h + 64 * rb, Ls);
}

// ---------------------------------------------------------------------------
// bf16 MFMA GEMM with fused per-sample correction (round-6/7 verified):
// GLL B-stage into linear [128][64] Bs with both-sides XOR swizzle.
// ---------------------------------------------------------------------------
#define LDB 72

template <int ZBF>
__global__ __launch_bounds__(256) void gemm_mfma(
    const float* __restrict__ Z, const unsigned short* __restrict__ Zbf,
    const unsigned short* __restrict__ Mbf, const float* __restrict__ MT,
    const int* __restrict__ tgt, const int* __restrict__ var,
    const float* __restrict__ means, const float* __restrict__ lsc,
    float* __restrict__ C) {
  __shared__ unsigned short As[128][LDB];
#if HAS_GLL
  __shared__ unsigned short Bs[128][64];
#else
  __shared__ unsigned short Bs[128][LDB];
#endif
  __shared__ float scoef[128];
  __shared__ int stb[128];

  const int d = blockIdx.x;
  const int xbl = d & 7;
  const int nir = (d >> 3) & 7;
  const int xbh = d >> 6;
  const int xb = xbh * 8 + xbl;
  const int ni = (xb & 32) ? (7 - nir) : nir;
  const int b0 = xb * 128;
  const int i0 = ni * 128;

  const int tid = threadIdx.x;
  const int w = tid >> 6;
  const int lane = tid & 63;
  const int wr = w >> 1, wc = w & 1;
  const int mlane = lane & 15;
  const int q = lane >> 4;

  const int rq = tid >> 4, kq = tid & 15;
  const int cb = tid >> 3, ck = tid & 7;

  f32x4 acc[4][4];
#pragma unroll
  for (int a = 0; a < 4; ++a)
#pragma unroll
    for (int b = 0; b < 4; ++b) acc[a][b] = (f32x4){0.f, 0.f, 0.f, 0.f};

  const int nkb = 2 * (ni + 1);
  for (int kb = 0; kb < nkb; ++kb) {
    const int k0 = kb * 64;
    if (ZBF) {
#pragma unroll
      for (int p = 0; p < 4; ++p) {
        const int r = p * 32 + cb;
        *(uint4*)&As[r][8 * ck] =
            *(const uint4*)(Zbf + (size_t)(b0 + r) * KDIM + k0 + 8 * ck);
      }
    } else {
#pragma unroll
      for (int p = 0; p < 8; ++p) {
        const int r = p * 16 + rq;
        float4 zv = *(const float4*)(Z + (size_t)(b0 + r) * KDIM + k0 + 4 * kq);
        ushort4 o;
        o.x = f2bf(zv.x);
        o.y = f2bf(zv.y);
        o.z = f2bf(zv.z);
        o.w = f2bf(zv.w);
        *(ushort4*)&As[r][4 * kq] = o;
      }
    }
#if HAS_GLL
    {
      const int rl = lane >> 3;
      const int ch = lane & 7;
#pragma unroll
      for (int i = 0; i < 4; ++i) {
        const int row = w * 32 + i * 8 + rl;
        const int sch = ch ^ (row & 7);
        const unsigned short* src =
            Mbf + (size_t)(i0 + row) * KDIM + k0 + sch * 8;
        __builtin_amdgcn_global_load_lds(
            (const __attribute__((address_space(1))) void*)src,
            (__attribute__((address_space(3))) void*)&Bs[w * 32 + i * 8][0],
            16, 0, 0);
      }
    }
#else
#pragma unroll
    for (int p = 0; p < 4; ++p) {
      const int c = p * 32 + cb;
      *(uint4*)&Bs[c][8 * ck] =
          *(const uint4*)(Mbf + (size_t)(i0 + c) * KDIM + k0 + 8 * ck);
    }
#endif
    __syncthreads();
#pragma unroll
    for (int ks = 0; ks < 2; ++ks) {
      const int kf = ks * 32 + q * 8;
      short8 av[4], bv[4];
#pragma unroll
      for (int a = 0; a < 4; ++a)
        av[a] = *(const short8*)&As[wr * 64 + 16 * a + mlane][kf];
#if HAS_GLL
      const char* BsB = (const char*)&Bs[0][0];
#pragma unroll
      for (int b = 0; b < 4; ++b) {
        const int row = wc * 64 + 16 * b + mlane;
        bv[b] = *(const short8*)(BsB + row * 128 +
                                 ((2 * kf) ^ ((row & 7) << 4)));
      }
#else
#pragma unroll
      for (int b = 0; b < 4; ++b)
        bv[b] = *(const short8*)&Bs[wc * 64 + 16 * b + mlane][kf];
#endif
#pragma unroll
      for (int a = 0; a < 4; ++a)
#pragma unroll
        for (int b = 0; b < 4; ++b)
          acc[a][b] =
              __builtin_amdgcn_mfma_f32_16x16x32_bf16(av[a], bv[b], acc[a][b], 0, 0, 0);
    }
    __syncthreads();
  }

  // ---- fused correction: coef for this block's 128 samples ----
  {
    const int s = tid >> 1, h2 = tid & 1;  // 2 threads per sample
    const int br = b0 + s;
    const int tb = tgt[br];
    float part = 0.f;
    if (tb >= 0) {
      const int nk16 = (tb >> 4) + 1;
      if (ZBF) {
        const unsigned short* zr = Zbf + (size_t)br * KDIM;
        const unsigned short* mr = Mbf + (size_t)tb * KDIM;
        for (int c16 = h2; c16 < nk16; c16 += 2) {
          const uint4 za = *(const uint4*)(zr + c16 * 16);
          const uint4 zb2 = *(const uint4*)(zr + c16 * 16 + 8);
          const uint4 ma = *(const uint4*)(mr + c16 * 16);
          const uint4 mb2 = *(const uint4*)(mr + c16 * 16 + 8);
          const unsigned zw[8] = {za.x, za.y, za.z, za.w,
                                  zb2.x, zb2.y, zb2.z, zb2.w};
          const unsigned mw[8] = {ma.x, ma.y, ma.z, ma.w,
                                  mb2.x, mb2.y, mb2.z, mb2.w};
#pragma unroll
          for (int wv = 0; wv < 8; ++wv) {
            part += __builtin_bit_cast(float, zw[wv] << 16) *
                    __builtin_bit_cast(float, mw[wv] << 16);
            part += __builtin_bit_cast(float, zw[wv] & 0xFFFF0000u) *
                    __builtin_bit_cast(float, mw[wv] & 0xFFFF0000u);
          }
        }
      } else {
        const float* zr = Z + (size_t)br * KDIM;
        const unsigned short* mr = Mbf + (size_t)tb * KDIM;
        const int nk8 = (tb >> 3) + 1;
        for (int c8 = h2; c8 < nk8; c8 += 2) {
          const float4 z0 = *(const float4*)(zr + c8 * 8);
          const float4 z1 = *(const float4*)(zr + c8 * 8 + 4);
          const ushort4 m0 = *(const ushort4*)(mr + c8 * 8);
          const ushort4 m1 = *(const ushort4*)(mr + c8 * 8 + 4);
          part += z0.x * bf2f(m0.x) + z0.y * bf2f(m0.y) + z0.z * bf2f(m0.z) +
                  z0.w * bf2f(m0.w) + z1.x * bf2f(m1.x) + z1.y * bf2f(m1.y) +
                  z1.z * bf2f(m1.z) + z1.w * bf2f(m1.w);
        }
      }
    }
    part += __shfl_down(part, 1);
    if (h2 == 0) {
      float cf = 0.f;
      int tbs = 0;
      if (tb >= 0) {
        const int v = var[br];
        const float mval = means[tb * VDIM + v];
        const float sval = expf(lsc[tb * VDIM + v]);
        const float zv = Z[(size_t)br * KDIM + tb];
        cf = (mval + sval * zv) - part;
        tbs = tb;
      }
      scoef[s] = cf;
      stb[s] = tbs;
    }
  }
  __syncthreads();

#pragma unroll
  for (int a = 0; a < 4; ++a) {
    const int l0 = wr * 64 + 16 * a + q * 4;
    const int row0 = b0 + l0;
#pragma unroll
    for (int b = 0; b < 4; ++b) {
      const int col = i0 + wc * 64 + 16 * b + mlane;
      float* Cp = C + (size_t)row0 * KDIM + col;
#pragma unroll
      for (int j = 0; j < 4; ++j) {
        const float cf = scoef[l0 + j];
        const float corr = cf * MT[(size_t)stb[l0 + j] * KDIM + col];
        Cp[j * KDIM] = acc[a][b][j] + corr;
      }
    }
  }
}

// ---------------------------------------------------------------------------
extern "C" void kernel_launch(void* const* d_in, const int* in_sizes, int n_in,
                              void* d_out, int out_size, void* d_ws,
                              size_t ws_size, hipStream_t stream) {
  const float* z = (const float*)d_in[0];
  const int* tgt = (const int*)d_in[1];
  const int* var = (const int*)d_in[2];
  const float* A = (const float*)d_in[3];
  const float* means = (const float*)d_in[4];
  const float* lsc = (const float*)d_in[5];
  float* out = (float*)d_out;

  char* ws = (char*)d_ws;
  float* MT = (float*)ws;                                    // 4 MB
  unsigned short* Mbf = (unsigned short*)(ws + (4u << 20));  // 2 MB
  float* Pt2 = (float*)(ws + (6u << 20));                    // 0.5 MB
  float* Pt3 = (float*)(ws + (6u << 20) + (512u << 10));     // 1 MB
  unsigned short* Zbf = (unsigned short*)(ws + (7u << 20) + (512u << 10));
  const int use_zbf =
      ws_size >= (7u << 20) + (512u << 10) + (size_t)BDIM * KDIM * 2 ? 1 : 0;

  hipLaunchKernelGGL(comb01, dim3(256), dim3(256), 0, stream, A, MT, Mbf, z,
                     Zbf, use_zbf);
  hipLaunchKernelGGL((p_k<4>), dim3(32), dim3(256), 0, stream, A, MT, Pt2);
  hipLaunchKernelGGL((q_k<4>), dim3(32), dim3(256), 0, stream, MT, Pt2, Mbf);
  hipLaunchKernelGGL((p_k<8>), dim3(64), dim3(256), 0, stream, A, MT, Pt3);
  hipLaunchKernelGGL((q_k<8>), dim3(64), dim3(256), 0, stream, MT, Pt3, Mbf);
  if (use_zbf)
    hipLaunchKernelGGL((gemm_mfma<1>), dim3((BDIM / 128) * (KDIM / 128)),
                       dim3(256), 0, stream, z, Zbf, Mbf, MT, tgt, var, means,
                       lsc, out);
  else
    hipLaunchKernelGGL((gemm_mfma<0>), dim3((BDIM / 128) * (KDIM / 128)),
                       dim3(256), 0, stream, z, Zbf, Mbf, MT, tgt, var, means,
                       lsc, out);
}

// Round 9
// 228.744 us; speedup vs baseline: 1.0864x; 1.0864x over previous
//
#include <hip/hip_runtime.h>
#include <hip/hip_bf16.h>
#include <cstdint>

#define KDIM 1024
#define BDIM 8192
#define VDIM 2
#define NBLK 16  // KDIM / 64

#if defined(__has_builtin)
#if __has_builtin(__builtin_amdgcn_global_load_lds)
#define HAS_GLL 1
#endif
#endif
#ifndef HAS_GLL
#define HAS_GLL 0
#endif

typedef __attribute__((ext_vector_type(8))) short short8;
typedef __attribute__((ext_vector_type(4))) float f32x4;

__device__ inline unsigned short f2bf(float x) {
  unsigned u = __builtin_bit_cast(unsigned, x);
  u = (u + 0x7FFFu + ((u >> 16) & 1u)) >> 16;
  return (unsigned short)u;
}

__device__ inline float bf2f(unsigned short x) {
  return __builtin_bit_cast(float, (unsigned)x << 16);
}

// q-output tile map: 96 64x64 MT tiles produced by lv2/lv3 comb_q.
// t<64: lv3 (bi 0..7, bj 8..15).  t>=64: lv2 (c in {0,1}).
__device__ inline void qtile_map(int t, int& bi, int& bj) {
  if (t < 64) {
    bi = t >> 3;
    bj = 8 + (t & 7);
  } else {
    int r = t - 64;
    const int c = r >> 4;
    r &= 15;
    bi = 8 * c + (r >> 2);
    bj = 8 * c + 4 + (r & 3);
  }
}

// ---------------------------------------------------------------------------
// Workspace layout (bytes from d_ws):
//   MT   @ 0        4 MB fp32   M^T (MT[t][i] = M[i][t])
//   Mbf  @ 4 MB     2 MB bf16   M row-major (Mbf[i][k] = M[i][k])
//   Pt2  @ 6 MB     0.5 MB      lv2 P scratch (atomic targets)
//   Pt3  @ 6.5 MB   1 MB        lv3 P scratch (atomic targets)
//   Zbf  @ 7.5 MB   16 MB       Z in bf16
// ---------------------------------------------------------------------------

// --------------------------- shared tile helpers ---------------------------
#define STAGE_T(DST, SRC, ROW0, COL0, LD)                                   \
  {                                                                         \
    const float* _s = (SRC);                                                \
    _Pragma("unroll") for (int _p = 0; _p < 4; ++_p) {                      \
      const int _m = _p * 16 + rw;                                          \
      float4 _v = *(const float4*)(_s + (size_t)((ROW0) + _m) * (LD) +      \
                                   (COL0) + 4 * k4);                        \
      (DST)[4 * k4 + 0][_m] = _v.x;                                         \
      (DST)[4 * k4 + 1][_m] = _v.y;                                         \
      (DST)[4 * k4 + 2][_m] = _v.z;                                         \
      (DST)[4 * k4 + 3][_m] = _v.w;                                         \
    }                                                                       \
  }

#define STAGE_D(DST, SRC, ROW0, COL0, LD)                                   \
  {                                                                         \
    const float* _s = (SRC);                                                \
    _Pragma("unroll") for (int _p = 0; _p < 4; ++_p) {                      \
      const int _kk = _p * 16 + rw;                                         \
      *(float4*)&(DST)[_kk][4 * k4] =                                       \
          *(const float4*)(_s + (size_t)((ROW0) + _kk) * (LD) + (COL0) +    \
                           4 * k4);                                         \
    }                                                                       \
  }

#define ZERO_ACC                                                            \
  _Pragma("unroll") for (int _a = 0; _a < 4; ++_a)                          \
      _Pragma("unroll") for (int _b = 0; _b < 4; ++_b) acc[_a][_b] = 0.f;

__device__ __forceinline__ void mac64(const float (*Ls)[68],
                                      const float (*Rs)[68], int tm, int tn,
                                      float acc[4][4]) {
#pragma unroll 4
  for (int k = 0; k < 64; ++k) {
    const float4 av = *(const float4*)&Ls[k][4 * tm];
    const float4 bv = *(const float4*)&Rs[k][4 * tn];
    const float aa[4] = {av.x, av.y, av.z, av.w};
    const float bb4[4] = {bv.x, bv.y, bv.z, bv.w};
#pragma unroll
    for (int a = 0; a < 4; ++a)
#pragma unroll
      for (int b = 0; b < 4; ++b) acc[a][b] += aa[a] * bb4[b];
  }
}

#define STORE_MT(R0, C0)                                                    \
  _Pragma("unroll") for (int _a = 0; _a < 4; ++_a) {                        \
    *(float4*)(MT + (size_t)((R0) + 4 * tm + _a) * KDIM + (C0) + 4 * tn) =  \
        make_float4(acc[_a][0], acc[_a][1], acc[_a][2], acc[_a][3]);        \
  }

#define MBF_TILE(R0, C0, BUF)                                               \
  {                                                                         \
    __syncthreads();                                                        \
    _Pragma("unroll") for (int _a = 0; _a < 4; ++_a)                        \
        _Pragma("unroll") for (int _b = 0; _b < 4; ++_b)                    \
            (BUF)[4 * tm + _a][4 * tn + _b] = acc[_a][_b];                  \
    __syncthreads();                                                        \
    const int _tr = tid >> 4, _tc = tid & 15;                               \
    _Pragma("unroll") for (int _p = 0; _p < 4; ++_p) {                      \
      const int _il = _p * 16 + _tr;                                        \
      ushort4 _o;                                                           \
      _o.x = f2bf((BUF)[4 * _tc + 0][_il]);                                 \
      _o.y = f2bf((BUF)[4 * _tc + 1][_il]);                                 \
      _o.z = f2bf((BUF)[4 * _tc + 2][_il]);                                 \
      _o.w = f2bf((BUF)[4 * _tc + 3][_il]);                                 \
      *(ushort4*)(Mbf + (size_t)((C0) + _il) * KDIM + (R0) + 4 * _tc) = _o; \
    }                                                                       \
  }

// ---------------------------------------------------------------------------
// comb01 (grid 256): blocks 0..15 = verified phase-0 (split-32 inversion) +
// verified lv0/lv1 body. Blocks 16..255 = streaming: MT strict-lower zero,
// MT q-region zero (atomic targets for comb_q), P scratch zero (atomic
// targets for comb_p), Mbf strict-upper zero, Z->bf16. All regions disjoint
// from comb01's tile writes.
// ---------------------------------------------------------------------------
__global__ __launch_bounds__(256) void comb01(const float* __restrict__ A,
                                              float* __restrict__ MT,
                                              unsigned short* __restrict__ Mbf,
                                              const float* __restrict__ Z,
                                              unsigned short* __restrict__ Zbf,
                                              float* __restrict__ Pscr,
                                              int do_zbf) {
  if (blockIdx.x >= NBLK) {
    const int wid = blockIdx.x - NBLK;
    const int nw = gridDim.x - NBLK;
    const int idx0 = wid * 256 + threadIdx.x;
    const int stride = nw * 256;
    const float4 z4 = make_float4(0.f, 0.f, 0.f, 0.f);
    const uint4 u4 = make_uint4(0u, 0u, 0u, 0u);

    // MT strict-lower zero (read by gemm-epilogue MT gather)
    for (int i = idx0; i < 256 * 1024; i += stride) {
      const int blk = i >> 10, off = i & 1023;
      const int bi = blk >> 4, bj = blk & 15;
      if (bi <= bj) continue;
      *(float4*)(MT + (size_t)(bi * 64 + (off >> 4)) * KDIM + bj * 64 +
                 4 * (off & 15)) = z4;
    }
    // MT q-region zero (96 tiles; comb_q atomic targets)
    for (int i = idx0; i < 96 * 1024; i += stride) {
      const int t = i >> 10, off = i & 1023;
      int bi, bj;
      qtile_map(t, bi, bj);
      *(float4*)(MT + (size_t)(bi * 64 + (off >> 4)) * KDIM + bj * 64 +
                 4 * (off & 15)) = z4;
    }
    // P scratch zero (Pt2+Pt3 contiguous: 1.5 MB = 98304 float4)
    for (int i = idx0; i < 98304; i += stride)
      *(float4*)(Pscr + 4 * (size_t)i) = z4;
    // Mbf strict-upper zero (read by gemm B-stage)
    for (int i = idx0; i < 256 * 512; i += stride) {
      const int blk = i >> 9, off = i & 511;
      const int bi = blk >> 4, bj = blk & 15;
      if (bi >= bj) continue;
      *(uint4*)(Mbf + (size_t)(bi * 64 + (off >> 3)) * KDIM + bj * 64 +
                8 * (off & 7)) = u4;
    }
    if (do_zbf) {
      for (int i = idx0; i < BDIM * KDIM / 4; i += stride) {
        float4 v = *(const float4*)(Z + 4 * (size_t)i);
        ushort4 o;
        o.x = f2bf(v.x);
        o.y = f2bf(v.y);
        o.z = f2bf(v.z);
        o.w = f2bf(v.w);
        *(ushort4*)(Zbf + 4 * (size_t)i) = o;
      }
    }
    return;
  }

  int b = blockIdx.x;
  const int rt = b & 1;
  const int jt = (b >> 1) & 1;
  const int s = b >> 2;
  const int base = s * 256;

  __shared__ float shpool[6 * 64 * 68];
  float (*Ls)[68] = (float(*)[68])(shpool);
  float (*Rs)[68] = (float(*)[68])(shpool + 4352);
  float (*tQ0L)[68] = (float(*)[68])(shpool + 2 * 4352);
  float (*tQ0H)[68] = (float(*)[68])(shpool + 3 * 4352);
  float (*tP0)[68] = (float(*)[68])(shpool + 4 * 4352);
  float (*tP1)[68] = (float(*)[68])(shpool + 5 * 4352);

  const int tid = threadIdx.x;
  const int k4 = tid & 15;
  const int rw = tid >> 4;
  const int tm = tid >> 4;
  const int tn = tid & 15;
  float acc[4][4];

  // ---- phase 0: invert the 4 diagonal blocks (split-32 + combine) ----
  {
    float* Tt = shpool;              // Tt[g][h][r][c] = g*2112 + h*1056 + r*33 + c
    float* As4 = shpool + 2 * 4352;  // 4 x [64][65]
    const int g = tid >> 6;          // wave -> diagonal 4s+g
    const int l = tid & 63;
    const int dbase = base + g * 64;
    float* Asg = As4 + g * 4160;

    for (int r = 0; r < 64; ++r)
      Asg[r * 65 + l] = A[(size_t)(dbase + r) * KDIM + dbase + l];
    __syncthreads();

    {
      const int h = l >> 5, c = l & 31;
      const float* Ah = Asg + (32 * h) * 65 + 32 * h;
      float m[32];
#pragma unroll
      for (int r = 0; r < 32; ++r) m[r] = (r == c) ? 1.f : 0.f;
#pragma unroll
      for (int r = 1; r < 32; ++r) {
        float a0 = 0.f, a1 = 0.f;
#pragma unroll
        for (int i = 0; i < 32; ++i) {
          if (i >= r) break;
          if (i & 1) a1 += Ah[r * 65 + i] * m[i];
          else       a0 += Ah[r * 65 + i] * m[i];
        }
        const float v = a0 + a1;
        m[r] = (r > c) ? v : m[r];
      }
      float* Th = Tt + g * 2112 + h * 1056;
#pragma unroll
      for (int r = 0; r < 32; ++r) Th[r * 33 + c] = m[r];
    }
    __syncthreads();

    const int tm8 = l >> 3, tn8 = l & 7;
    {
      float u[4][4];
#pragma unroll
      for (int a = 0; a < 4; ++a)
#pragma unroll
        for (int b2 = 0; b2 < 4; ++b2) u[a][b2] = 0.f;
      const float* T1 = Tt + g * 2112;
#pragma unroll
      for (int ki = 0; ki < 8; ++ki) {
        float4 av[4], bv[4];
#pragma unroll
        for (int a = 0; a < 4; ++a)
          av[a] = *(const float4*)&Asg[(32 + 4 * tm8 + a) * 65 + 4 * ki];
#pragma unroll
        for (int j = 0; j < 4; ++j)
          bv[j] = *(const float4*)&T1[(4 * ki + j) * 33 + 4 * tn8];
#pragma unroll
        for (int a = 0; a < 4; ++a) {
          const float aa[4] = {av[a].x, av[a].y, av[a].z, av[a].w};
#pragma unroll
          for (int j = 0; j < 4; ++j) {
            const float bb[4] = {bv[j].x, bv[j].y, bv[j].z, bv[j].w};
#pragma unroll
            for (int b2 = 0; b2 < 4; ++b2) u[a][b2] += aa[j] * bb[b2];
          }
        }
      }
#pragma unroll
      for (int a = 0; a < 4; ++a)
#pragma unroll
        for (int b2 = 0; b2 < 4; ++b2)
          Asg[(4 * tm8 + a) * 32 + 4 * tn8 + b2] = u[a][b2];
    }
    __syncthreads();

    {
      float t21[4][4];
#pragma unroll
      for (int a = 0; a < 4; ++a)
#pragma unroll
        for (int b2 = 0; b2 < 4; ++b2) t21[a][b2] = 0.f;
      const float* T2 = Tt + g * 2112 + 1056;
#pragma unroll
      for (int ki = 0; ki < 8; ++ki) {
        float4 av[4], bv[4];
#pragma unroll
        for (int a = 0; a < 4; ++a)
          av[a] = *(const float4*)&T2[(4 * tm8 + a) * 33 + 4 * ki];
#pragma unroll
        for (int j = 0; j < 4; ++j)
          bv[j] = *(const float4*)&Asg[(4 * ki + j) * 32 + 4 * tn8];
#pragma unroll
        for (int a = 0; a < 4; ++a) {
          const float aa[4] = {av[a].x, av[a].y, av[a].z, av[a].w};
#pragma unroll
          for (int j = 0; j < 4; ++j) {
            const float bb[4] = {bv[j].x, bv[j].y, bv[j].z, bv[j].w};
#pragma unroll
            for (int b2 = 0; b2 < 4; ++b2) t21[a][b2] += aa[j] * bb[b2];
          }
        }
      }
#pragma unroll
      for (int a = 0; a < 4; ++a)
#pragma unroll
        for (int b2 = 0; b2 < 4; ++b2)
          Asg[1024 + (4 * tm8 + a) * 32 + 4 * tn8 + b2] = t21[a][b2];
    }
    __syncthreads();

    {
      const float* T21 = Asg + 1024;
      const float* Tg = Tt + g * 2112;
      for (int r4 = 0; r4 < 16; ++r4) {
        float vals[4];
#pragma unroll
        for (int j = 0; j < 4; ++j) {
          const int r = 4 * r4 + j;
          float v;
          if (r < 32)
            v = (l < 32) ? Tg[r * 33 + l] : 0.f;
          else
            v = (l < 32) ? T21[(r - 32) * 32 + l]
                         : Tg[1056 + (r - 32) * 33 + (l - 32)];
          vals[j] = v;
        }
        *(float4*)(MT + (size_t)(dbase + l) * KDIM + dbase + 4 * r4) =
            make_float4(vals[0], vals[1], vals[2], vals[3]);
      }
      if (jt == 0 && rt == 0) {
        for (int r = 0; r < 64; ++r) {
          float v;
          if (r < 32)
            v = (l < 32) ? Tg[r * 33 + l] : 0.f;
          else
            v = (l < 32) ? T21[(r - 32) * 32 + l]
                         : Tg[1056 + (r - 32) * 33 + (l - 32)];
          Mbf[(size_t)(dbase + r) * KDIM + dbase + l] = f2bf(v);
        }
      }
    }
    __syncthreads();
  }

  // ---- verified comb01 body (rounds 3-8) ----
  if (jt == 0) {
    STAGE_T(Ls, MT, base, base, KDIM);
    STAGE_T(Rs, A, base + 64, base, KDIM);
    __syncthreads();
    ZERO_ACC;
    mac64(Ls, Rs, tm, tn, acc);
    __syncthreads();
#pragma unroll
    for (int a = 0; a < 4; ++a)
#pragma unroll
      for (int b2 = 0; b2 < 4; ++b2) tP0[4 * tn + b2][4 * tm + a] = acc[a][b2];
    STAGE_D(Rs, MT, base + 64, base + 64, KDIM);
    __syncthreads();
    ZERO_ACC;
    mac64(tP0, Rs, tm, tn, acc);
    __syncthreads();
#pragma unroll
    for (int a = 0; a < 4; ++a)
#pragma unroll
      for (int b2 = 0; b2 < 4; ++b2) tQ0L[4 * tn + b2][4 * tm + a] = acc[a][b2];
    if (rt == 0) {
      STORE_MT(base, base + 64);
      MBF_TILE(base, base + 64, Rs);
    }
  }
  __syncthreads();

  if (rt == 1) {
    STAGE_T(Ls, MT, base + 128, base + 128, KDIM);
    STAGE_T(Rs, A, base + 192, base + 128, KDIM);
    __syncthreads();
    ZERO_ACC;
    mac64(Ls, Rs, tm, tn, acc);
    __syncthreads();
#pragma unroll
    for (int a = 0; a < 4; ++a)
#pragma unroll
      for (int b2 = 0; b2 < 4; ++b2) tP1[4 * tn + b2][4 * tm + a] = acc[a][b2];
    STAGE_D(Rs, MT, base + 192, base + 192, KDIM);
    __syncthreads();
    ZERO_ACC;
    mac64(tP1, Rs, tm, tn, acc);
    __syncthreads();
#pragma unroll
    for (int a = 0; a < 4; ++a)
#pragma unroll
      for (int b2 = 0; b2 < 4; ++b2) tQ0H[4 * tm + a][4 * tn + b2] = acc[a][b2];
    if (jt == 1) {
      STORE_MT(base + 128, base + 192);
      MBF_TILE(base + 128, base + 192, Rs);
    }
  }
  __syncthreads();

  STAGE_T(Ls, MT, base + 64 * jt, base + 64 * jt, KDIM);
  __syncthreads();
  for (int kb2 = 0; kb2 <= rt; ++kb2) {
    ZERO_ACC;
    for (int kb = jt; kb < 2; ++kb) {
      STAGE_T(Rs, A, base + 128 + 64 * kb2, base + 64 * kb, KDIM);
      __syncthreads();
      mac64(kb == jt ? Ls : tQ0L, Rs, tm, tn, acc);
      __syncthreads();
    }
    if (kb2 == 0) {
#pragma unroll
      for (int a = 0; a < 4; ++a)
#pragma unroll
        for (int b2 = 0; b2 < 4; ++b2) tP0[4 * tn + b2][4 * tm + a] = acc[a][b2];
    } else {
#pragma unroll
      for (int a = 0; a < 4; ++a)
#pragma unroll
        for (int b2 = 0; b2 < 4; ++b2) tP1[4 * tn + b2][4 * tm + a] = acc[a][b2];
    }
  }
  __syncthreads();

  ZERO_ACC;
  if (rt == 0) {
    STAGE_D(Rs, MT, base + 128, base + 128, KDIM);
    __syncthreads();
    mac64(tP0, Rs, tm, tn, acc);
    __syncthreads();
  } else {
    mac64(tP0, tQ0H, tm, tn, acc);
    __syncthreads();
    STAGE_D(Rs, MT, base + 192, base + 192, KDIM);
    __syncthreads();
    mac64(tP1, Rs, tm, tn, acc);
    __syncthreads();
  }
  STORE_MT(base + 64 * jt, base + 128 + 64 * rt);
  MBF_TILE(base + 64 * jt, base + 128 + 64 * rt, Rs);
}

// ---------------------------------------------------------------------------
// Split-K atomic combine (round-0-verified shape, triangular-pruned):
// one stage + one mac64 + atomic accumulation per block -> full parallelism.
// comb_p<T>: Pt(jt,rt) += M11^T(jt,kc) x A21(rt,kc); prune kc<jt (MT zero).
// comb_q<T>: MT(jt, h+rt) += Pt(jt,kc) x M22^T(kc,rt); prune kc>rt.
// grid = combines * T^3.
// ---------------------------------------------------------------------------
template <int T>
__global__ __launch_bounds__(256) void comb_p(const float* __restrict__ A,
                                              const float* __restrict__ MT,
                                              float* __restrict__ Pt) {
  int b = blockIdx.x;
  const int kc = b % T; b /= T;
  const int rt = b % T; b /= T;
  const int jt = b % T; b /= T;
  const int c = b;
  if (kc < jt) return;
  const int h = 64 * T;
  const int base = c * 2 * h;

  __shared__ float Ls[64][68];
  __shared__ float Rs[64][68];
  const int tid = threadIdx.x;
  const int k4 = tid & 15;
  const int rw = tid >> 4;
  const int tm = tid >> 4;
  const int tn = tid & 15;
  float acc[4][4];
  ZERO_ACC;

  STAGE_T(Ls, MT, base + 64 * jt, base + 64 * kc, KDIM);
  STAGE_T(Rs, A, base + h + 64 * rt, base + 64 * kc, KDIM);
  __syncthreads();
  mac64(Ls, Rs, tm, tn, acc);

  float* P0 = Pt + (size_t)c * h * h;
#pragma unroll
  for (int a = 0; a < 4; ++a)
#pragma unroll
    for (int b2 = 0; b2 < 4; ++b2)
      unsafeAtomicAdd(P0 + (size_t)(64 * jt + 4 * tm + a) * h + 64 * rt +
                          4 * tn + b2,
                      acc[a][b2]);
}

template <int T>
__global__ __launch_bounds__(256) void comb_q(float* __restrict__ MT,
                                              const float* __restrict__ Pt) {
  int b = blockIdx.x;
  const int kc = b % T; b /= T;
  const int rt = b % T; b /= T;
  const int jt = b % T; b /= T;
  const int c = b;
  if (kc > rt) return;
  const int h = 64 * T;
  const int base = c * 2 * h;

  __shared__ float Ls[64][68];
  __shared__ float Rs[64][68];
  const int tid = threadIdx.x;
  const int k4 = tid & 15;
  const int rw = tid >> 4;
  const int tm = tid >> 4;
  const int tn = tid & 15;
  float acc[4][4];
  ZERO_ACC;

  const float* P0 = Pt + (size_t)c * h * h;
  STAGE_T(Ls, P0, 64 * jt, 64 * kc, h);
  STAGE_D(Rs, MT, base + h + 64 * kc, base + h + 64 * rt, KDIM);
  __syncthreads();
  mac64(Ls, Rs, tm, tn, acc);

#pragma unroll
  for (int a = 0; a < 4; ++a)
#pragma unroll
    for (int b2 = 0; b2 < 4; ++b2)
      unsafeAtomicAdd(MT + (size_t)(base + 64 * jt + 4 * tm + a) * KDIM +
                          base + h + 64 * rt + 4 * tn + b2,
                      acc[a][b2]);
}

// ---------------------------------------------------------------------------
// mt2bf96: bf16-mirror the 96 q-output MT tiles into Mbf (round-3-verified
// transpose+convert body).  Mbf[i][k] = bf16(MT[k][i]).
// ---------------------------------------------------------------------------
__global__ __launch_bounds__(256) void mt2bf96(const float* __restrict__ MT,
                                               unsigned short* __restrict__ Mbf) {
  int bi, bj;
  qtile_map(blockIdx.x, bi, bj);
  const int j0 = bi * 64;  // MT row block
  const int i0 = bj * 64;  // MT col block = Mbf row block
  __shared__ float tile[64][65];

  const int tr = threadIdx.x >> 4;
  const int tc = threadIdx.x & 15;
#pragma unroll
  for (int p = 0; p < 4; ++p) {
    const int rj = p * 16 + tr;
    float4 v = *(const float4*)(MT + (size_t)(j0 + rj) * KDIM + i0 + 4 * tc);
    tile[rj][4 * tc + 0] = v.x;
    tile[rj][4 * tc + 1] = v.y;
    tile[rj][4 * tc + 2] = v.z;
    tile[rj][4 * tc + 3] = v.w;
  }
  __syncthreads();
#pragma unroll
  for (int p = 0; p < 4; ++p) {
    const int il = p * 16 + tr;
    ushort4 o;
    o.x = f2bf(tile[4 * tc + 0][il]);
    o.y = f2bf(tile[4 * tc + 1][il]);
    o.z = f2bf(tile[4 * tc + 2][il]);
    o.w = f2bf(tile[4 * tc + 3][il]);
    *(ushort4*)(Mbf + (size_t)(i0 + il) * KDIM + j0 + 4 * tc) = o;
  }
}

// ---------------------------------------------------------------------------
// bf16 MFMA GEMM with fused per-sample correction (round-6/7/8 verified):
// GLL B-stage into linear [128][64] Bs with both-sides XOR swizzle.
// ---------------------------------------------------------------------------
#define LDB 72

template <int ZBF>
__global__ __launch_bounds__(256) void gemm_mfma(
    const float* __restrict__ Z, const unsigned short* __restrict__ Zbf,
    const unsigned short* __restrict__ Mbf, const float* __restrict__ MT,
    const int* __restrict__ tgt, const int* __restrict__ var,
    const float* __restrict__ means, const float* __restrict__ lsc,
    float* __restrict__ C) {
  __shared__ unsigned short As[128][LDB];
#if HAS_GLL
  __shared__ unsigned short Bs[128][64];
#else
  __shared__ unsigned short Bs[128][LDB];
#endif
  __shared__ float scoef[128];
  __shared__ int stb[128];

  const int d = blockIdx.x;
  const int xbl = d & 7;
  const int nir = (d >> 3) & 7;
  const int xbh = d >> 6;
  const int xb = xbh * 8 + xbl;
  const int ni = (xb & 32) ? (7 - nir) : nir;
  const int b0 = xb * 128;
  const int i0 = ni * 128;

  const int tid = threadIdx.x;
  const int w = tid >> 6;
  const int lane = tid & 63;
  const int wr = w >> 1, wc = w & 1;
  const int mlane = lane & 15;
  const int q = lane >> 4;

  const int rq = tid >> 4, kq = tid & 15;
  const int cb = tid >> 3, ck = tid & 7;

  f32x4 acc[4][4];
#pragma unroll
  for (int a = 0; a < 4; ++a)
#pragma unroll
    for (int b = 0; b < 4; ++b) acc[a][b] = (f32x4){0.f, 0.f, 0.f, 0.f};

  const int nkb = 2 * (ni + 1);
  for (int kb = 0; kb < nkb; ++kb) {
    const int k0 = kb * 64;
    if (ZBF) {
#pragma unroll
      for (int p = 0; p < 4; ++p) {
        const int r = p * 32 + cb;
        *(uint4*)&As[r][8 * ck] =
            *(const uint4*)(Zbf + (size_t)(b0 + r) * KDIM + k0 + 8 * ck);
      }
    } else {
#pragma unroll
      for (int p = 0; p < 8; ++p) {
        const int r = p * 16 + rq;
        float4 zv = *(const float4*)(Z + (size_t)(b0 + r) * KDIM + k0 + 4 * kq);
        ushort4 o;
        o.x = f2bf(zv.x);
        o.y = f2bf(zv.y);
        o.z = f2bf(zv.z);
        o.w = f2bf(zv.w);
        *(ushort4*)&As[r][4 * kq] = o;
      }
    }
#if HAS_GLL
    {
      const int rl = lane >> 3;
      const int ch = lane & 7;
#pragma unroll
      for (int i = 0; i < 4; ++i) {
        const int row = w * 32 + i * 8 + rl;
        const int sch = ch ^ (row & 7);
        const unsigned short* src =
            Mbf + (size_t)(i0 + row) * KDIM + k0 + sch * 8;
        __builtin_amdgcn_global_load_lds(
            (const __attribute__((address_space(1))) void*)src,
            (__attribute__((address_space(3))) void*)&Bs[w * 32 + i * 8][0],
            16, 0, 0);
      }
    }
#else
#pragma unroll
    for (int p = 0; p < 4; ++p) {
      const int c = p * 32 + cb;
      *(uint4*)&Bs[c][8 * ck] =
          *(const uint4*)(Mbf + (size_t)(i0 + c) * KDIM + k0 + 8 * ck);
    }
#endif
    __syncthreads();
#pragma unroll
    for (int ks = 0; ks < 2; ++ks) {
      const int kf = ks * 32 + q * 8;
      short8 av[4], bv[4];
#pragma unroll
      for (int a = 0; a < 4; ++a)
        av[a] = *(const short8*)&As[wr * 64 + 16 * a + mlane][kf];
#if HAS_GLL
      const char* BsB = (const char*)&Bs[0][0];
#pragma unroll
      for (int b = 0; b < 4; ++b) {
        const int row = wc * 64 + 16 * b + mlane;
        bv[b] = *(const short8*)(BsB + row * 128 +
                                 ((2 * kf) ^ ((row & 7) << 4)));
      }
#else
#pragma unroll
      for (int b = 0; b < 4; ++b)
        bv[b] = *(const short8*)&Bs[wc * 64 + 16 * b + mlane][kf];
#endif
#pragma unroll
      for (int a = 0; a < 4; ++a)
#pragma unroll
        for (int b = 0; b < 4; ++b)
          acc[a][b] =
              __builtin_amdgcn_mfma_f32_16x16x32_bf16(av[a], bv[b], acc[a][b], 0, 0, 0);
    }
    __syncthreads();
  }

  // ---- fused correction: coef for this block's 128 samples ----
  {
    const int s = tid >> 1, h2 = tid & 1;  // 2 threads per sample
    const int br = b0 + s;
    const int tb = tgt[br];
    float part = 0.f;
    if (tb >= 0) {
      const int nk16 = (tb >> 4) + 1;
      if (ZBF) {
        const unsigned short* zr = Zbf + (size_t)br * KDIM;
        const unsigned short* mr = Mbf + (size_t)tb * KDIM;
        for (int c16 = h2; c16 < nk16; c16 += 2) {
          const uint4 za = *(const uint4*)(zr + c16 * 16);
          const uint4 zb2 = *(const uint4*)(zr + c16 * 16 + 8);
          const uint4 ma = *(const uint4*)(mr + c16 * 16);
          const uint4 mb2 = *(const uint4*)(mr + c16 * 16 + 8);
          const unsigned zw[8] = {za.x, za.y, za.z, za.w,
                                  zb2.x, zb2.y, zb2.z, zb2.w};
          const unsigned mw[8] = {ma.x, ma.y, ma.z, ma.w,
                                  mb2.x, mb2.y, mb2.z, mb2.w};
#pragma unroll
          for (int wv = 0; wv < 8; ++wv) {
            part += __builtin_bit_cast(float, zw[wv] << 16) *
                    __builtin_bit_cast(float, mw[wv] << 16);
            part += __builtin_bit_cast(float, zw[wv] & 0xFFFF0000u) *
                    __builtin_bit_cast(float, mw[wv] & 0xFFFF0000u);
          }
        }
      } else {
        const float* zr = Z + (size_t)br * KDIM;
        const unsigned short* mr = Mbf + (size_t)tb * KDIM;
        const int nk8 = (tb >> 3) + 1;
        for (int c8 = h2; c8 < nk8; c8 += 2) {
          const float4 z0 = *(const float4*)(zr + c8 * 8);
          const float4 z1 = *(const float4*)(zr + c8 * 8 + 4);
          const ushort4 m0 = *(const ushort4*)(mr + c8 * 8);
          const ushort4 m1 = *(const ushort4*)(mr + c8 * 8 + 4);
          part += z0.x * bf2f(m0.x) + z0.y * bf2f(m0.y) + z0.z * bf2f(m0.z) +
                  z0.w * bf2f(m0.w) + z1.x * bf2f(m1.x) + z1.y * bf2f(m1.y) +
                  z1.z * bf2f(m1.z) + z1.w * bf2f(m1.w);
        }
      }
    }
    part += __shfl_down(part, 1);
    if (h2 == 0) {
      float cf = 0.f;
      int tbs = 0;
      if (tb >= 0) {
        const int v = var[br];
        const float mval = means[tb * VDIM + v];
        const float sval = expf(lsc[tb * VDIM + v]);
        const float zv = Z[(size_t)br * KDIM + tb];
        cf = (mval + sval * zv) - part;
        tbs = tb;
      }
      scoef[s] = cf;
      stb[s] = tbs;
    }
  }
  __syncthreads();

#pragma unroll
  for (int a = 0; a < 4; ++a) {
    const int l0 = wr * 64 + 16 * a + q * 4;
    const int row0 = b0 + l0;
#pragma unroll
    for (int b = 0; b < 4; ++b) {
      const int col = i0 + wc * 64 + 16 * b + mlane;
      float* Cp = C + (size_t)row0 * KDIM + col;
#pragma unroll
      for (int j = 0; j < 4; ++j) {
        const float cf = scoef[l0 + j];
        const float corr = cf * MT[(size_t)stb[l0 + j] * KDIM + col];
        Cp[j * KDIM] = acc[a][b][j] + corr;
      }
    }
  }
}

// ---------------------------------------------------------------------------
extern "C" void kernel_launch(void* const* d_in, const int* in_sizes, int n_in,
                              void* d_out, int out_size, void* d_ws,
                              size_t ws_size, hipStream_t stream) {
  const float* z = (const float*)d_in[0];
  const int* tgt = (const int*)d_in[1];
  const int* var = (const int*)d_in[2];
  const float* A = (const float*)d_in[3];
  const float* means = (const float*)d_in[4];
  const float* lsc = (const float*)d_in[5];
  float* out = (float*)d_out;

  char* ws = (char*)d_ws;
  float* MT = (float*)ws;                                    // 4 MB
  unsigned short* Mbf = (unsigned short*)(ws + (4u << 20));  // 2 MB
  float* Pt2 = (float*)(ws + (6u << 20));                    // 0.5 MB
  float* Pt3 = (float*)(ws + (6u << 20) + (512u << 10));     // 1 MB
  unsigned short* Zbf = (unsigned short*)(ws + (7u << 20) + (512u << 10));
  const int use_zbf =
      ws_size >= (7u << 20) + (512u << 10) + (size_t)BDIM * KDIM * 2 ? 1 : 0;

  hipLaunchKernelGGL(comb01, dim3(256), dim3(256), 0, stream, A, MT, Mbf, z,
                     Zbf, Pt2, use_zbf);
  hipLaunchKernelGGL((comb_p<4>), dim3(128), dim3(256), 0, stream, A, MT, Pt2);
  hipLaunchKernelGGL((comb_q<4>), dim3(128), dim3(256), 0, stream, MT, Pt2);
  hipLaunchKernelGGL((comb_p<8>), dim3(512), dim3(256), 0, stream, A, MT, Pt3);
  hipLaunchKernelGGL((comb_q<8>), dim3(512), dim3(256), 0, stream, MT, Pt3);
  hipLaunchKernelGGL(mt2bf96, dim3(96), dim3(256), 0, stream, MT, Mbf);
  if (use_zbf)
    hipLaunchKernelGGL((gemm_mfma<1>), dim3((BDIM / 128) * (KDIM / 128)),
                       dim3(256), 0, stream, z, Zbf, Mbf, MT, tgt, var, means,
                       lsc, out);
  else
    hipLaunchKernelGGL((gemm_mfma<0>), dim3((BDIM / 128) * (KDIM / 128)),
                       dim3(256), 0, stream, z, Zbf, Mbf, MT, tgt, var, means,
                       lsc, out);
}

// Round 10
// 213.905 us; speedup vs baseline: 1.1618x; 1.0694x over previous
//
#include <hip/hip_runtime.h>
#include <hip/hip_bf16.h>
#include <cstdint>

#define KDIM 1024
#define BDIM 8192
#define VDIM 2
#define NBLK 16  // KDIM / 64

#if defined(__has_builtin)
#if __has_builtin(__builtin_amdgcn_global_load_lds)
#define HAS_GLL 1
#endif
#endif
#ifndef HAS_GLL
#define HAS_GLL 0
#endif

typedef __attribute__((ext_vector_type(8))) short short8;
typedef __attribute__((ext_vector_type(4))) float f32x4;

__device__ inline unsigned short f2bf(float x) {
  unsigned u = __builtin_bit_cast(unsigned, x);
  u = (u + 0x7FFFu + ((u >> 16) & 1u)) >> 16;
  return (unsigned short)u;
}

__device__ inline float bf2f(unsigned short x) {
  return __builtin_bit_cast(float, (unsigned)x << 16);
}

// q-output tile map: 112 64x64 MT tiles produced by lv1/lv2/lv3 comb_q.
// t<64: lv3 (bi 0..7, bj 8..15). 64<=t<96: lv2. 96<=t<112: lv1.
__device__ inline void qtile_map(int t, int& bi, int& bj) {
  if (t < 64) {
    bi = t >> 3;
    bj = 8 + (t & 7);
  } else if (t < 96) {
    int r = t - 64;
    const int c = r >> 4;
    r &= 15;
    bi = 8 * c + (r >> 2);
    bj = 8 * c + 4 + (r & 3);
  } else {
    int r = t - 96;
    const int c = r >> 2;
    r &= 3;
    bi = 4 * c + (r >> 1);
    bj = 4 * c + 2 + (r & 1);
  }
}

// ---------------------------------------------------------------------------
// Workspace layout (bytes from d_ws):
//   MT   @ 0        4 MB fp32   M^T (MT[t][i] = M[i][t])
//   Mbf  @ 4 MB     2 MB bf16   M row-major
//   Pt1  @ 6 MB     256 KB      lv1 P scratch (atomic targets)
//   Pt2  @ 6.25 MB  512 KB      lv2 P scratch
//   Pt3  @ 6.75 MB  1 MB        lv3 P scratch
//   Zbf  @ 7.75 MB  16 MB       Z in bf16
// ---------------------------------------------------------------------------

// --------------------------- shared tile helpers ---------------------------
#define STAGE_T(DST, SRC, ROW0, COL0, LD)                                   \
  {                                                                         \
    const float* _s = (SRC);                                                \
    _Pragma("unroll") for (int _p = 0; _p < 4; ++_p) {                      \
      const int _m = _p * 16 + rw;                                          \
      float4 _v = *(const float4*)(_s + (size_t)((ROW0) + _m) * (LD) +      \
                                   (COL0) + 4 * k4);                        \
      (DST)[4 * k4 + 0][_m] = _v.x;                                         \
      (DST)[4 * k4 + 1][_m] = _v.y;                                         \
      (DST)[4 * k4 + 2][_m] = _v.z;                                         \
      (DST)[4 * k4 + 3][_m] = _v.w;                                         \
    }                                                                       \
  }

#define STAGE_D(DST, SRC, ROW0, COL0, LD)                                   \
  {                                                                         \
    const float* _s = (SRC);                                                \
    _Pragma("unroll") for (int _p = 0; _p < 4; ++_p) {                      \
      const int _kk = _p * 16 + rw;                                         \
      *(float4*)&(DST)[_kk][4 * k4] =                                       \
          *(const float4*)(_s + (size_t)((ROW0) + _kk) * (LD) + (COL0) +    \
                           4 * k4);                                         \
    }                                                                       \
  }

#define ZERO_ACC                                                            \
  _Pragma("unroll") for (int _a = 0; _a < 4; ++_a)                          \
      _Pragma("unroll") for (int _b = 0; _b < 4; ++_b) acc[_a][_b] = 0.f;

__device__ __forceinline__ void mac64(const float (*Ls)[68],
                                      const float (*Rs)[68], int tm, int tn,
                                      float acc[4][4]) {
#pragma unroll 4
  for (int k = 0; k < 64; ++k) {
    const float4 av = *(const float4*)&Ls[k][4 * tm];
    const float4 bv = *(const float4*)&Rs[k][4 * tn];
    const float aa[4] = {av.x, av.y, av.z, av.w};
    const float bb4[4] = {bv.x, bv.y, bv.z, bv.w};
#pragma unroll
    for (int a = 0; a < 4; ++a)
#pragma unroll
      for (int b = 0; b < 4; ++b) acc[a][b] += aa[a] * bb4[b];
  }
}

#define STORE_MT(R0, C0)                                                    \
  _Pragma("unroll") for (int _a = 0; _a < 4; ++_a) {                        \
    *(float4*)(MT + (size_t)((R0) + 4 * tm + _a) * KDIM + (C0) + 4 * tn) =  \
        make_float4(acc[_a][0], acc[_a][1], acc[_a][2], acc[_a][3]);        \
  }

#define MBF_TILE(R0, C0, BUF)                                               \
  {                                                                         \
    __syncthreads();                                                        \
    _Pragma("unroll") for (int _a = 0; _a < 4; ++_a)                        \
        _Pragma("unroll") for (int _b = 0; _b < 4; ++_b)                    \
            (BUF)[4 * tm + _a][4 * tn + _b] = acc[_a][_b];                  \
    __syncthreads();                                                        \
    const int _tr = tid >> 4, _tc = tid & 15;                               \
    _Pragma("unroll") for (int _p = 0; _p < 4; ++_p) {                      \
      const int _il = _p * 16 + _tr;                                        \
      ushort4 _o;                                                           \
      _o.x = f2bf((BUF)[4 * _tc + 0][_il]);                                 \
      _o.y = f2bf((BUF)[4 * _tc + 1][_il]);                                 \
      _o.z = f2bf((BUF)[4 * _tc + 2][_il]);                                 \
      _o.w = f2bf((BUF)[4 * _tc + 3][_il]);                                 \
      *(ushort4*)(Mbf + (size_t)((C0) + _il) * KDIM + (R0) + 4 * _tc) = _o; \
    }                                                                       \
  }

// ---------------------------------------------------------------------------
// comb0a (grid 256): blocks 0..7 = one per 64-pair p: phase-0 split-32
// inversion of diagonals 2p,2p+1 (verified r7 code, 2 waves) + the lv0
// combine for the pair (2 mac64, verified body) + MT/Mbf writes.
// Blocks 8..255 = streaming: MT strict-lower zero, MT q-region zero
// (112 tiles = lv1+lv2+lv3 comb_q atomic targets), P scratch zero
// (Pt1+Pt2+Pt3 = 1.75 MB), Mbf strict-upper zero, Z->bf16.
// All streaming regions are disjoint from comb0a's tile writes.
// ---------------------------------------------------------------------------
__global__ __launch_bounds__(256) void comb0a(const float* __restrict__ A,
                                              float* __restrict__ MT,
                                              unsigned short* __restrict__ Mbf,
                                              const float* __restrict__ Z,
                                              unsigned short* __restrict__ Zbf,
                                              float* __restrict__ Pscr,
                                              int do_zbf) {
  if (blockIdx.x >= 8) {
    const int wid = blockIdx.x - 8;
    const int nw = gridDim.x - 8;
    const int idx0 = wid * 256 + threadIdx.x;
    const int stride = nw * 256;
    const float4 z4 = make_float4(0.f, 0.f, 0.f, 0.f);
    const uint4 u4 = make_uint4(0u, 0u, 0u, 0u);

    // MT strict-lower zero (gemm-epilogue MT gather reads)
    for (int i = idx0; i < 256 * 1024; i += stride) {
      const int blk = i >> 10, off = i & 1023;
      const int bi = blk >> 4, bj = blk & 15;
      if (bi <= bj) continue;
      *(float4*)(MT + (size_t)(bi * 64 + (off >> 4)) * KDIM + bj * 64 +
                 4 * (off & 15)) = z4;
    }
    // MT q-region zero (112 tiles; comb_q atomic targets)
    for (int i = idx0; i < 112 * 1024; i += stride) {
      const int t = i >> 10, off = i & 1023;
      int bi, bj;
      qtile_map(t, bi, bj);
      *(float4*)(MT + (size_t)(bi * 64 + (off >> 4)) * KDIM + bj * 64 +
                 4 * (off & 15)) = z4;
    }
    // P scratch zero (Pt1+Pt2+Pt3 contiguous: 1.75 MB = 114688 float4)
    for (int i = idx0; i < 114688; i += stride)
      *(float4*)(Pscr + 4 * (size_t)i) = z4;
    // Mbf strict-upper zero (gemm B-stage reads)
    for (int i = idx0; i < 256 * 512; i += stride) {
      const int blk = i >> 9, off = i & 511;
      const int bi = blk >> 4, bj = blk & 15;
      if (bi >= bj) continue;
      *(uint4*)(Mbf + (size_t)(bi * 64 + (off >> 3)) * KDIM + bj * 64 +
                8 * (off & 7)) = u4;
    }
    if (do_zbf) {
      for (int i = idx0; i < BDIM * KDIM / 4; i += stride) {
        float4 v = *(const float4*)(Z + 4 * (size_t)i);
        ushort4 o;
        o.x = f2bf(v.x);
        o.y = f2bf(v.y);
        o.z = f2bf(v.z);
        o.w = f2bf(v.w);
        *(ushort4*)(Zbf + 4 * (size_t)i) = o;
      }
    }
    return;
  }

  const int p = blockIdx.x;
  const int pb = p * 128;

  __shared__ float pool[3 * 4352];  // 52.2 KB
  float (*Ls)[68] = (float(*)[68])(pool);
  float (*Rs)[68] = (float(*)[68])(pool + 4352);
  float (*tP0)[68] = (float(*)[68])(pool + 2 * 4352);

  const int tid = threadIdx.x;
  const int k4 = tid & 15;
  const int rw = tid >> 4;
  const int tm = tid >> 4;
  const int tn = tid & 15;
  float acc[4][4];

  // ---- phase 0: invert diagonals 2p (wave 0) and 2p+1 (wave 1) ----
  {
    float* Tt = pool;                // 2 x 2112 floats (T1,T2 per diag)
    float* As2 = pool + 4352;        // 2 x [64][65]
    const int g = tid >> 6;          // wave id
    const int l = tid & 63;
    const int dbase = pb + g * 64;
    float* Asg = As2 + g * 4160;

    if (g < 2) {
      for (int r = 0; r < 64; ++r)
        Asg[r * 65 + l] = A[(size_t)(dbase + r) * KDIM + dbase + l];
    }
    __syncthreads();

    if (g < 2) {
      const int h = l >> 5, c = l & 31;
      const float* Ah = Asg + (32 * h) * 65 + 32 * h;
      float m[32];
#pragma unroll
      for (int r = 0; r < 32; ++r) m[r] = (r == c) ? 1.f : 0.f;
#pragma unroll
      for (int r = 1; r < 32; ++r) {
        float a0 = 0.f, a1 = 0.f;
#pragma unroll
        for (int i = 0; i < 32; ++i) {
          if (i >= r) break;
          if (i & 1) a1 += Ah[r * 65 + i] * m[i];
          else       a0 += Ah[r * 65 + i] * m[i];
        }
        const float v = a0 + a1;
        m[r] = (r > c) ? v : m[r];
      }
      float* Th = Tt + g * 2112 + h * 1056;
#pragma unroll
      for (int r = 0; r < 32; ++r) Th[r * 33 + c] = m[r];
    }
    __syncthreads();

    const int tm8 = (tid & 63) >> 3, tn8 = tid & 7;
    if (g < 2) {
      // U = A21 * T1 (32x32)
      float u[4][4];
#pragma unroll
      for (int a = 0; a < 4; ++a)
#pragma unroll
        for (int b2 = 0; b2 < 4; ++b2) u[a][b2] = 0.f;
      const float* T1 = Tt + g * 2112;
#pragma unroll
      for (int ki = 0; ki < 8; ++ki) {
        float4 av[4], bv[4];
#pragma unroll
        for (int a = 0; a < 4; ++a)
          av[a] = *(const float4*)&Asg[(32 + 4 * tm8 + a) * 65 + 4 * ki];
#pragma unroll
        for (int j = 0; j < 4; ++j)
          bv[j] = *(const float4*)&T1[(4 * ki + j) * 33 + 4 * tn8];
#pragma unroll
        for (int a = 0; a < 4; ++a) {
          const float aa[4] = {av[a].x, av[a].y, av[a].z, av[a].w};
#pragma unroll
          for (int j = 0; j < 4; ++j) {
            const float bb[4] = {bv[j].x, bv[j].y, bv[j].z, bv[j].w};
#pragma unroll
            for (int b2 = 0; b2 < 4; ++b2) u[a][b2] += aa[j] * bb[b2];
          }
        }
      }
#pragma unroll
      for (int a = 0; a < 4; ++a)
#pragma unroll
        for (int b2 = 0; b2 < 4; ++b2)
          Asg[(4 * tm8 + a) * 32 + 4 * tn8 + b2] = u[a][b2];
    }
    __syncthreads();

    if (g < 2) {
      // T21 = T2 * U (32x32)
      float t21[4][4];
#pragma unroll
      for (int a = 0; a < 4; ++a)
#pragma unroll
        for (int b2 = 0; b2 < 4; ++b2) t21[a][b2] = 0.f;
      const float* T2 = Tt + g * 2112 + 1056;
#pragma unroll
      for (int ki = 0; ki < 8; ++ki) {
        float4 av[4], bv[4];
#pragma unroll
        for (int a = 0; a < 4; ++a)
          av[a] = *(const float4*)&T2[(4 * tm8 + a) * 33 + 4 * ki];
#pragma unroll
        for (int j = 0; j < 4; ++j)
          bv[j] = *(const float4*)&Asg[(4 * ki + j) * 32 + 4 * tn8];
#pragma unroll
        for (int a = 0; a < 4; ++a) {
          const float aa[4] = {av[a].x, av[a].y, av[a].z, av[a].w};
#pragma unroll
          for (int j = 0; j < 4; ++j) {
            const float bb[4] = {bv[j].x, bv[j].y, bv[j].z, bv[j].w};
#pragma unroll
            for (int b2 = 0; b2 < 4; ++b2) t21[a][b2] += aa[j] * bb[b2];
          }
        }
      }
#pragma unroll
      for (int a = 0; a < 4; ++a)
#pragma unroll
        for (int b2 = 0; b2 < 4; ++b2)
          Asg[1024 + (4 * tm8 + a) * 32 + 4 * tn8 + b2] = t21[a][b2];
    }
    __syncthreads();

    if (g < 2) {
      // write T to MT (lane l = column) + Mbf mirror
      const float* T21 = Asg + 1024;
      const float* Tg = Tt + g * 2112;
      for (int r4 = 0; r4 < 16; ++r4) {
        float vals[4];
#pragma unroll
        for (int j = 0; j < 4; ++j) {
          const int r = 4 * r4 + j;
          float v;
          if (r < 32)
            v = (l < 32) ? Tg[r * 33 + l] : 0.f;
          else
            v = (l < 32) ? T21[(r - 32) * 32 + l]
                         : Tg[1056 + (r - 32) * 33 + (l - 32)];
          vals[j] = v;
        }
        *(float4*)(MT + (size_t)(dbase + l) * KDIM + dbase + 4 * r4) =
            make_float4(vals[0], vals[1], vals[2], vals[3]);
      }
      for (int r = 0; r < 64; ++r) {
        float v;
        if (r < 32)
          v = (l < 32) ? Tg[r * 33 + l] : 0.f;
        else
          v = (l < 32) ? T21[(r - 32) * 32 + l]
                       : Tg[1056 + (r - 32) * 33 + (l - 32)];
        Mbf[(size_t)(dbase + r) * KDIM + dbase + l] = f2bf(v);
      }
    }
    __syncthreads();
  }

  // ---- lv0 combine for pair p (verified body, base -> pb) ----
  STAGE_T(Ls, MT, pb, pb, KDIM);          // T_{2p}
  STAGE_T(Rs, A, pb + 64, pb, KDIM);      // A21
  __syncthreads();
  ZERO_ACC;
  mac64(Ls, Rs, tm, tn, acc);
  __syncthreads();
#pragma unroll
  for (int a = 0; a < 4; ++a)
#pragma unroll
    for (int b2 = 0; b2 < 4; ++b2) tP0[4 * tn + b2][4 * tm + a] = acc[a][b2];
  STAGE_D(Rs, MT, pb + 64, pb + 64, KDIM);  // T_{2p+1}
  __syncthreads();
  ZERO_ACC;
  mac64(tP0, Rs, tm, tn, acc);
  STORE_MT(pb, pb + 64);
  MBF_TILE(pb, pb + 64, Rs);
}

// ---------------------------------------------------------------------------
// Split-K atomic combine (round-9 verified template, now also used at T=2):
// comb_p<T>: Pt(jt,rt) += M11^T(jt,kc) x A21(rt,kc); prune kc<jt.
// comb_q<T>: MT(jt, h+rt) += Pt(jt,kc) x M22^T(kc,rt); prune kc>rt.
// grid = combines * T^3.
// ---------------------------------------------------------------------------
template <int T>
__global__ __launch_bounds__(256) void comb_p(const float* __restrict__ A,
                                              const float* __restrict__ MT,
                                              float* __restrict__ Pt) {
  int b = blockIdx.x;
  const int kc = b % T; b /= T;
  const int rt = b % T; b /= T;
  const int jt = b % T; b /= T;
  const int c = b;
  if (kc < jt) return;
  const int h = 64 * T;
  const int base = c * 2 * h;

  __shared__ float Ls[64][68];
  __shared__ float Rs[64][68];
  const int tid = threadIdx.x;
  const int k4 = tid & 15;
  const int rw = tid >> 4;
  const int tm = tid >> 4;
  const int tn = tid & 15;
  float acc[4][4];
  ZERO_ACC;

  STAGE_T(Ls, MT, base + 64 * jt, base + 64 * kc, KDIM);
  STAGE_T(Rs, A, base + h + 64 * rt, base + 64 * kc, KDIM);
  __syncthreads();
  mac64(Ls, Rs, tm, tn, acc);

  float* P0 = Pt + (size_t)c * h * h;
#pragma unroll
  for (int a = 0; a < 4; ++a)
#pragma unroll
    for (int b2 = 0; b2 < 4; ++b2)
      unsafeAtomicAdd(P0 + (size_t)(64 * jt + 4 * tm + a) * h + 64 * rt +
                          4 * tn + b2,
                      acc[a][b2]);
}

template <int T>
__global__ __launch_bounds__(256) void comb_q(float* __restrict__ MT,
                                              const float* __restrict__ Pt) {
  int b = blockIdx.x;
  const int kc = b % T; b /= T;
  const int rt = b % T; b /= T;
  const int jt = b % T; b /= T;
  const int c = b;
  if (kc > rt) return;
  const int h = 64 * T;
  const int base = c * 2 * h;

  __shared__ float Ls[64][68];
  __shared__ float Rs[64][68];
  const int tid = threadIdx.x;
  const int k4 = tid & 15;
  const int rw = tid >> 4;
  const int tm = tid >> 4;
  const int tn = tid & 15;
  float acc[4][4];
  ZERO_ACC;

  const float* P0 = Pt + (size_t)c * h * h;
  STAGE_T(Ls, P0, 64 * jt, 64 * kc, h);
  STAGE_D(Rs, MT, base + h + 64 * kc, base + h + 64 * rt, KDIM);
  __syncthreads();
  mac64(Ls, Rs, tm, tn, acc);

#pragma unroll
  for (int a = 0; a < 4; ++a)
#pragma unroll
    for (int b2 = 0; b2 < 4; ++b2)
      unsafeAtomicAdd(MT + (size_t)(base + 64 * jt + 4 * tm + a) * KDIM +
                          base + h + 64 * rt + 4 * tn + b2,
                      acc[a][b2]);
}

// ---------------------------------------------------------------------------
// mt2bf112: bf16-mirror the 112 q-output MT tiles into Mbf.
// ---------------------------------------------------------------------------
__global__ __launch_bounds__(256) void mt2bf112(const float* __restrict__ MT,
                                                unsigned short* __restrict__ Mbf) {
  int bi, bj;
  qtile_map(blockIdx.x, bi, bj);
  const int j0 = bi * 64;  // MT row block
  const int i0 = bj * 64;  // MT col block = Mbf row block
  __shared__ float tile[64][65];

  const int tr = threadIdx.x >> 4;
  const int tc = threadIdx.x & 15;
#pragma unroll
  for (int p = 0; p < 4; ++p) {
    const int rj = p * 16 + tr;
    float4 v = *(const float4*)(MT + (size_t)(j0 + rj) * KDIM + i0 + 4 * tc);
    tile[rj][4 * tc + 0] = v.x;
    tile[rj][4 * tc + 1] = v.y;
    tile[rj][4 * tc + 2] = v.z;
    tile[rj][4 * tc + 3] = v.w;
  }
  __syncthreads();
#pragma unroll
  for (int p = 0; p < 4; ++p) {
    const int il = p * 16 + tr;
    ushort4 o;
    o.x = f2bf(tile[4 * tc + 0][il]);
    o.y = f2bf(tile[4 * tc + 1][il]);
    o.z = f2bf(tile[4 * tc + 2][il]);
    o.w = f2bf(tile[4 * tc + 3][il]);
    *(ushort4*)(Mbf + (size_t)(i0 + il) * KDIM + j0 + 4 * tc) = o;
  }
}

// ---------------------------------------------------------------------------
// bf16 MFMA GEMM with fused per-sample correction (round-6..9 verified):
// GLL B-stage into linear [128][64] Bs with both-sides XOR swizzle.
// ---------------------------------------------------------------------------
#define LDB 72

template <int ZBF>
__global__ __launch_bounds__(256) void gemm_mfma(
    const float* __restrict__ Z, const unsigned short* __restrict__ Zbf,
    const unsigned short* __restrict__ Mbf, const float* __restrict__ MT,
    const int* __restrict__ tgt, const int* __restrict__ var,
    const float* __restrict__ means, const float* __restrict__ lsc,
    float* __restrict__ C) {
  __shared__ unsigned short As[128][LDB];
#if HAS_GLL
  __shared__ unsigned short Bs[128][64];
#else
  __shared__ unsigned short Bs[128][LDB];
#endif
  __shared__ float scoef[128];
  __shared__ int stb[128];

  const int d = blockIdx.x;
  const int xbl = d & 7;
  const int nir = (d >> 3) & 7;
  const int xbh = d >> 6;
  const int xb = xbh * 8 + xbl;
  const int ni = (xb & 32) ? (7 - nir) : nir;
  const int b0 = xb * 128;
  const int i0 = ni * 128;

  const int tid = threadIdx.x;
  const int w = tid >> 6;
  const int lane = tid & 63;
  const int wr = w >> 1, wc = w & 1;
  const int mlane = lane & 15;
  const int q = lane >> 4;

  const int rq = tid >> 4, kq = tid & 15;
  const int cb = tid >> 3, ck = tid & 7;

  f32x4 acc[4][4];
#pragma unroll
  for (int a = 0; a < 4; ++a)
#pragma unroll
    for (int b = 0; b < 4; ++b) acc[a][b] = (f32x4){0.f, 0.f, 0.f, 0.f};

  const int nkb = 2 * (ni + 1);
  for (int kb = 0; kb < nkb; ++kb) {
    const int k0 = kb * 64;
    if (ZBF) {
#pragma unroll
      for (int p = 0; p < 4; ++p) {
        const int r = p * 32 + cb;
        *(uint4*)&As[r][8 * ck] =
            *(const uint4*)(Zbf + (size_t)(b0 + r) * KDIM + k0 + 8 * ck);
      }
    } else {
#pragma unroll
      for (int p = 0; p < 8; ++p) {
        const int r = p * 16 + rq;
        float4 zv = *(const float4*)(Z + (size_t)(b0 + r) * KDIM + k0 + 4 * kq);
        ushort4 o;
        o.x = f2bf(zv.x);
        o.y = f2bf(zv.y);
        o.z = f2bf(zv.z);
        o.w = f2bf(zv.w);
        *(ushort4*)&As[r][4 * kq] = o;
      }
    }
#if HAS_GLL
    {
      const int rl = lane >> 3;
      const int ch = lane & 7;
#pragma unroll
      for (int i = 0; i < 4; ++i) {
        const int row = w * 32 + i * 8 + rl;
        const int sch = ch ^ (row & 7);
        const unsigned short* src =
            Mbf + (size_t)(i0 + row) * KDIM + k0 + sch * 8;
        __builtin_amdgcn_global_load_lds(
            (const __attribute__((address_space(1))) void*)src,
            (__attribute__((address_space(3))) void*)&Bs[w * 32 + i * 8][0],
            16, 0, 0);
      }
    }
#else
#pragma unroll
    for (int p = 0; p < 4; ++p) {
      const int c = p * 32 + cb;
      *(uint4*)&Bs[c][8 * ck] =
          *(const uint4*)(Mbf + (size_t)(i0 + c) * KDIM + k0 + 8 * ck);
    }
#endif
    __syncthreads();
#pragma unroll
    for (int ks = 0; ks < 2; ++ks) {
      const int kf = ks * 32 + q * 8;
      short8 av[4], bv[4];
#pragma unroll
      for (int a = 0; a < 4; ++a)
        av[a] = *(const short8*)&As[wr * 64 + 16 * a + mlane][kf];
#if HAS_GLL
      const char* BsB = (const char*)&Bs[0][0];
#pragma unroll
      for (int b = 0; b < 4; ++b) {
        const int row = wc * 64 + 16 * b + mlane;
        bv[b] = *(const short8*)(BsB + row * 128 +
                                 ((2 * kf) ^ ((row & 7) << 4)));
      }
#else
#pragma unroll
      for (int b = 0; b < 4; ++b)
        bv[b] = *(const short8*)&Bs[wc * 64 + 16 * b + mlane][kf];
#endif
#pragma unroll
      for (int a = 0; a < 4; ++a)
#pragma unroll
        for (int b = 0; b < 4; ++b)
          acc[a][b] =
              __builtin_amdgcn_mfma_f32_16x16x32_bf16(av[a], bv[b], acc[a][b], 0, 0, 0);
    }
    __syncthreads();
  }

  // ---- fused correction: coef for this block's 128 samples ----
  {
    const int s = tid >> 1, h2 = tid & 1;  // 2 threads per sample
    const int br = b0 + s;
    const int tb = tgt[br];
    float part = 0.f;
    if (tb >= 0) {
      const int nk16 = (tb >> 4) + 1;
      if (ZBF) {
        const unsigned short* zr = Zbf + (size_t)br * KDIM;
        const unsigned short* mr = Mbf + (size_t)tb * KDIM;
        for (int c16 = h2; c16 < nk16; c16 += 2) {
          const uint4 za = *(const uint4*)(zr + c16 * 16);
          const uint4 zb2 = *(const uint4*)(zr + c16 * 16 + 8);
          const uint4 ma = *(const uint4*)(mr + c16 * 16);
          const uint4 mb2 = *(const uint4*)(mr + c16 * 16 + 8);
          const unsigned zw[8] = {za.x, za.y, za.z, za.w,
                                  zb2.x, zb2.y, zb2.z, zb2.w};
          const unsigned mw[8] = {ma.x, ma.y, ma.z, ma.w,
                                  mb2.x, mb2.y, mb2.z, mb2.w};
#pragma unroll
          for (int wv = 0; wv < 8; ++wv) {
            part += __builtin_bit_cast(float, zw[wv] << 16) *
                    __builtin_bit_cast(float, mw[wv] << 16);
            part += __builtin_bit_cast(float, zw[wv] & 0xFFFF0000u) *
                    __builtin_bit_cast(float, mw[wv] & 0xFFFF0000u);
          }
        }
      } else {
        const float* zr = Z + (size_t)br * KDIM;
        const unsigned short* mr = Mbf + (size_t)tb * KDIM;
        const int nk8 = (tb >> 3) + 1;
        for (int c8 = h2; c8 < nk8; c8 += 2) {
          const float4 z0 = *(const float4*)(zr + c8 * 8);
          const float4 z1 = *(const float4*)(zr + c8 * 8 + 4);
          const ushort4 m0 = *(const ushort4*)(mr + c8 * 8);
          const ushort4 m1 = *(const ushort4*)(mr + c8 * 8 + 4);
          part += z0.x * bf2f(m0.x) + z0.y * bf2f(m0.y) + z0.z * bf2f(m0.z) +
                  z0.w * bf2f(m0.w) + z1.x * bf2f(m1.x) + z1.y * bf2f(m1.y) +
                  z1.z * bf2f(m1.z) + z1.w * bf2f(m1.w);
        }
      }
    }
    part += __shfl_down(part, 1);
    if (h2 == 0) {
      float cf = 0.f;
      int tbs = 0;
      if (tb >= 0) {
        const int v = var[br];
        const float mval = means[tb * VDIM + v];
        const float sval = expf(lsc[tb * VDIM + v]);
        const float zv = Z[(size_t)br * KDIM + tb];
        cf = (mval + sval * zv) - part;
        tbs = tb;
      }
      scoef[s] = cf;
      stb[s] = tbs;
    }
  }
  __syncthreads();

#pragma unroll
  for (int a = 0; a < 4; ++a) {
    const int l0 = wr * 64 + 16 * a + q * 4;
    const int row0 = b0 + l0;
#pragma unroll
    for (int b = 0; b < 4; ++b) {
      const int col = i0 + wc * 64 + 16 * b + mlane;
      float* Cp = C + (size_t)row0 * KDIM + col;
#pragma unroll
      for (int j = 0; j < 4; ++j) {
        const float cf = scoef[l0 + j];
        const float corr = cf * MT[(size_t)stb[l0 + j] * KDIM + col];
        Cp[j * KDIM] = acc[a][b][j] + corr;
      }
    }
  }
}

// ---------------------------------------------------------------------------
extern "C" void kernel_launch(void* const* d_in, const int* in_sizes, int n_in,
                              void* d_out, int out_size, void* d_ws,
                              size_t ws_size, hipStream_t stream) {
  const float* z = (const float*)d_in[0];
  const int* tgt = (const int*)d_in[1];
  const int* var = (const int*)d_in[2];
  const float* A = (const float*)d_in[3];
  const float* means = (const float*)d_in[4];
  const float* lsc = (const float*)d_in[5];
  float* out = (float*)d_out;

  char* ws = (char*)d_ws;
  float* MT = (float*)ws;                                       // 4 MB
  unsigned short* Mbf = (unsigned short*)(ws + (4u << 20));     // 2 MB
  float* Pt1 = (float*)(ws + (6u << 20));                       // 256 KB
  float* Pt2 = (float*)(ws + (6u << 20) + (256u << 10));        // 512 KB
  float* Pt3 = (float*)(ws + (6u << 20) + (768u << 10));        // 1 MB
  unsigned short* Zbf = (unsigned short*)(ws + (7u << 20) + (768u << 10));
  const int use_zbf =
      ws_size >= (7u << 20) + (768u << 10) + (size_t)BDIM * KDIM * 2 ? 1 : 0;

  hipLaunchKernelGGL(comb0a, dim3(256), dim3(256), 0, stream, A, MT, Mbf, z,
                     Zbf, Pt1, use_zbf);
  hipLaunchKernelGGL((comb_p<2>), dim3(32), dim3(256), 0, stream, A, MT, Pt1);
  hipLaunchKernelGGL((comb_q<2>), dim3(32), dim3(256), 0, stream, MT, Pt1);
  hipLaunchKernelGGL((comb_p<4>), dim3(128), dim3(256), 0, stream, A, MT, Pt2);
  hipLaunchKernelGGL((comb_q<4>), dim3(128), dim3(256), 0, stream, MT, Pt2);
  hipLaunchKernelGGL((comb_p<8>), dim3(512), dim3(256), 0, stream, A, MT, Pt3);
  hipLaunchKernelGGL((comb_q<8>), dim3(512), dim3(256), 0, stream, MT, Pt3);
  hipLaunchKernelGGL(mt2bf112, dim3(112), dim3(256), 0, stream, MT, Mbf);
  if (use_zbf)
    hipLaunchKernelGGL((gemm_mfma<1>), dim3((BDIM / 128) * (KDIM / 128)),
                       dim3(256), 0, stream, z, Zbf, Mbf, MT, tgt, var, means,
                       lsc, out);
  else
    hipLaunchKernelGGL((gemm_mfma<0>), dim3((BDIM / 128) * (KDIM / 128)),
                       dim3(256), 0, stream, z, Zbf, Mbf, MT, tgt, var, means,
                       lsc, out);
}